// Round 2
// 256.859 us; speedup vs baseline: 1.0142x; 1.0142x over previous
//
#include <hip/hip_runtime.h>
#include <hip/hip_fp16.h>
#include <math.h>

#define CAP 64          // max incidences per node (mean deg = 8)
#define D1 128
#define D2 16
#define C_OUT 40
#define K_EDGE 32
#define CLAMP_LO 1e-7f
#define CLAMP_HI 10.0f
#define SQRT_INV31 0.1796053020267749f   // sqrt(1/31)

typedef unsigned short ushort_t;
typedef _Float16 h2v __attribute__((ext_vector_type(2)));   // packed fp16 pair

// Fused setup: clip+square -> Hp (fp16), incidence-list build (uint16 edge
// ids), W1 transpose, and zero rows of S/S2.
__global__ __launch_bounds__(256) void k_setup(const float* __restrict__ x,
                                               __half2* __restrict__ Hp,
                                               const int* __restrict__ idx,
                                               int* __restrict__ deg,
                                               ushort_t* __restrict__ lst,
                                               const float* __restrict__ W1,
                                               float* __restrict__ W1t,
                                               __half2* __restrict__ S,
                                               float* __restrict__ S2,
                                               int n4, int total, int E) {
    int i = blockIdx.x * 256 + threadIdx.x;
    if (i < n4) {                                  // clip + square, 4 floats
        float4 v = ((const float4*)x)[i];
        v.x = fminf(fmaxf(v.x, CLAMP_LO), CLAMP_HI);
        v.y = fminf(fmaxf(v.y, CLAMP_LO), CLAMP_HI);
        v.z = fminf(fmaxf(v.z, CLAMP_LO), CLAMP_HI);
        v.w = fminf(fmaxf(v.w, CLAMP_LO), CLAMP_HI);
        Hp[2 * i]     = __floats2half2_rn(v.x * v.x, v.y * v.y);
        Hp[2 * i + 1] = __floats2half2_rn(v.z * v.z, v.w * v.w);
    }
    if (i < total) {                               // incidence build
        int n = idx[i];
        int e = i >> 5;                            // k = 32
        int pos = atomicAdd(&deg[n], 1);
        if (pos < CAP) lst[n * CAP + pos] = (ushort_t)e;
    }
    if (i < D1 * D2) W1t[(i & 15) * D1 + (i >> 4)] = W1[i];
    if (i < 64) S[(size_t)E * 64 + i] = __floats2half2_rn(0.0f, 0.0f);
    if (i < D2) S2[(size_t)E * D2 + i] = 0.0f;
}

// S[e,:] = sum of Hp[node,:] over the edge's 32 nodes. TWO edges per wave:
// one coalesced 64-id load covers edges eA and eA+1; 64 saddr gathers in
// flight; idx-load/store fixed costs amortized. 8 edges per 256-block.
__global__ __launch_bounds__(256) void k_edge_sum(const __half2* __restrict__ Hp,
                                                  const int* __restrict__ idx,
                                                  __half2* __restrict__ S, int E) {
    int w = threadIdx.x >> 6;
    int lane = threadIdx.x & 63;
    int eA = blockIdx.x * 8 + w * 2;            // E % 8 == 0
    int nid = idx[eA * K_EDGE + lane];          // 32 ids of eA + 32 ids of eA+1
    float a0 = 0.0f, a1 = 0.0f, b0 = 0.0f, b1 = 0.0f;
#pragma unroll
    for (int j = 0; j < K_EDGE; j++) {
        int nA = __builtin_amdgcn_readlane(nid, j);
        int nB = __builtin_amdgcn_readlane(nid, 32 + j);
        __half2 hA = Hp[(size_t)nA * 64 + lane];
        __half2 hB = Hp[(size_t)nB * 64 + lane];
        a0 += __low2float(hA); a1 += __high2float(hA);
        b0 += __low2float(hB); b1 += __high2float(hB);
    }
    S[(size_t)eA * 64 + lane]       = __floats2half2_rn(a0, a1);
    S[(size_t)(eA + 1) * 64 + lane] = __floats2half2_rn(b0, b1);
}

// Fused layer-1 node kernel. TWO nodes per wave; uint16 lst with only slots
// 0..15 loaded (lanes 0-15: node0, 16-31: node1). Zero-row padding: unused
// slots carry edge id E (row E of S is zeros) so sqrt(max(0-hp,0)) == 0.
// Degree-adaptive: slots processed in 8+4+4 blocks gated by max(dg0,dg1)
// (wave-uniform branch; mean deg = 8 so ~30% of slot work is skipped).
// Inner diff+clamp packed fp16 (v_pk_add/max_f16 via ext-vector _Float16).
__global__ __launch_bounds__(256) void k_node1(const __half2* __restrict__ Hp,
                                               const __half2* __restrict__ S,
                                               const int* __restrict__ deg,
                                               const ushort_t* __restrict__ lst,
                                               const float* __restrict__ W1t,
                                               const float* __restrict__ b1,
                                               float* __restrict__ Hp2, int N, int E) {
    int w = threadIdx.x >> 6;
    int lane = threadIdx.x & 63;
    int pair = blockIdx.x * 4 + w;              // wave handles nodes 2p, 2p+1
    int n0 = pair * 2, n1 = n0 + 1;             // N even
    int c = lane & 15, j = lane >> 4;

    int2 dg2 = ((const int2*)deg)[pair];
    int dg0 = min(dg2.x, CAP), dg1 = min(dg2.y, CAP);
    int sl = lane & 15;
    int nodesel = (lane < 16) ? n0 : n1;
    ushort_t idu = (lane < 32) ? lst[nodesel * CAP + sl] : (ushort_t)0;
    int dsel = (lane < 16) ? dg0 : dg1;
    int e_sel = (lane < 32 && sl < dsel) ? (int)idu : E;

    __half2 hph0 = Hp[(size_t)n0 * 64 + lane];
    __half2 hph1 = Hp[(size_t)n1 * 64 + lane];
    h2v hp0v, hp1v;
    __builtin_memcpy(&hp0v, &hph0, 4);
    __builtin_memcpy(&hp1v, &hph1, 4);
    const h2v zv = (h2v)(_Float16)0.0f;

    int dmaxc = min(max(dg0, dg1), 16);

    float a00 = 0.0f, a01 = 0.0f, a10 = 0.0f, a11 = 0.0f;

    // ---- block 1: slots 0..7 (always; covers deg <= 8, P ~ 0.55/node) ----
    h2v sA[8], sB[8];
#pragma unroll
    for (int t = 0; t < 8; t++) {
        int e = __builtin_amdgcn_readlane(e_sel, t);
        __half2 hv = S[(size_t)e * 64 + lane];
        __builtin_memcpy(&sA[t], &hv, 4);
    }
#pragma unroll
    for (int t = 0; t < 8; t++) {
        int e = __builtin_amdgcn_readlane(e_sel, 16 + t);
        __half2 hv = S[(size_t)e * 64 + lane];
        __builtin_memcpy(&sB[t], &hv, 4);
    }
#pragma unroll
    for (int t = 0; t < 8; t++) {
        h2v d0 = __builtin_elementwise_max(sA[t] - hp0v, zv);
        h2v d1 = __builtin_elementwise_max(sB[t] - hp1v, zv);
        a00 += __builtin_amdgcn_sqrtf((float)d0[0]);
        a01 += __builtin_amdgcn_sqrtf((float)d0[1]);
        a10 += __builtin_amdgcn_sqrtf((float)d1[0]);
        a11 += __builtin_amdgcn_sqrtf((float)d1[1]);
    }

    // ---- block 2: slots 8..11 (taken by ~70% of waves) ----
    if (dmaxc > 8) {
        h2v tA[4], tB[4];
#pragma unroll
        for (int t = 0; t < 4; t++) {
            int e = __builtin_amdgcn_readlane(e_sel, 8 + t);
            __half2 hv = S[(size_t)e * 64 + lane];
            __builtin_memcpy(&tA[t], &hv, 4);
        }
#pragma unroll
        for (int t = 0; t < 4; t++) {
            int e = __builtin_amdgcn_readlane(e_sel, 24 + t);
            __half2 hv = S[(size_t)e * 64 + lane];
            __builtin_memcpy(&tB[t], &hv, 4);
        }
#pragma unroll
        for (int t = 0; t < 4; t++) {
            h2v d0 = __builtin_elementwise_max(tA[t] - hp0v, zv);
            h2v d1 = __builtin_elementwise_max(tB[t] - hp1v, zv);
            a00 += __builtin_amdgcn_sqrtf((float)d0[0]);
            a01 += __builtin_amdgcn_sqrtf((float)d0[1]);
            a10 += __builtin_amdgcn_sqrtf((float)d1[0]);
            a11 += __builtin_amdgcn_sqrtf((float)d1[1]);
        }

        // ---- block 3: slots 12..15 (taken by ~12% of waves) ----
        if (dmaxc > 12) {
            h2v uA[4], uB[4];
#pragma unroll
            for (int t = 0; t < 4; t++) {
                int e = __builtin_amdgcn_readlane(e_sel, 12 + t);
                __half2 hv = S[(size_t)e * 64 + lane];
                __builtin_memcpy(&uA[t], &hv, 4);
            }
#pragma unroll
            for (int t = 0; t < 4; t++) {
                int e = __builtin_amdgcn_readlane(e_sel, 28 + t);
                __half2 hv = S[(size_t)e * 64 + lane];
                __builtin_memcpy(&uB[t], &hv, 4);
            }
#pragma unroll
            for (int t = 0; t < 4; t++) {
                h2v d0 = __builtin_elementwise_max(uA[t] - hp0v, zv);
                h2v d1 = __builtin_elementwise_max(uB[t] - hp1v, zv);
                a00 += __builtin_amdgcn_sqrtf((float)d0[0]);
                a01 += __builtin_amdgcn_sqrtf((float)d0[1]);
                a10 += __builtin_amdgcn_sqrtf((float)d1[0]);
                a11 += __builtin_amdgcn_sqrtf((float)d1[1]);
            }
        }
    }

    float hp00 = __low2float(hph0), hp01 = __high2float(hph0);
    float hp10 = __low2float(hph1), hp11 = __high2float(hph1);

    for (int t = 16; t < dg0; t++) {            // rare tails (P ~ 0.4%)
        int e = lst[n0 * CAP + t];
        __half2 sh = S[(size_t)e * 64 + lane];
        a00 += __builtin_amdgcn_sqrtf(fmaxf(__low2float(sh)  - hp00, 0.0f));
        a01 += __builtin_amdgcn_sqrtf(fmaxf(__high2float(sh) - hp01, 0.0f));
    }
    for (int t = 16; t < dg1; t++) {
        int e = lst[n1 * CAP + t];
        __half2 sh = S[(size_t)e * 64 + lane];
        a10 += __builtin_amdgcn_sqrtf(fmaxf(__low2float(sh)  - hp10, 0.0f));
        a11 += __builtin_amdgcn_sqrtf(fmaxf(__high2float(sh) - hp11, 0.0f));
    }

    float ns00 = __builtin_amdgcn_sqrtf(hp00) + a00 * SQRT_INV31;
    float ns01 = __builtin_amdgcn_sqrtf(hp01) + a01 * SQRT_INV31;
    float ns10 = __builtin_amdgcn_sqrtf(hp10) + a10 * SQRT_INV31;
    float ns11 = __builtin_amdgcn_sqrtf(hp11) + a11 * SQRT_INV31;

    __shared__ float AHs[4][2][D1];             // wave-private
    AHs[w][0][2 * lane]     = ns00;
    AHs[w][0][2 * lane + 1] = ns01;
    AHs[w][1][2 * lane]     = ns10;
    AHs[w][1][2 * lane + 1] = ns11;

    float v0 = ns00 + ns01, v1 = ns10 + ns11;
#pragma unroll
    for (int m = 1; m < 64; m <<= 1) {
        v0 += __shfl_xor(v0, m, 64);
        v1 += __shfl_xor(v1, m, 64);
    }
    float r0 = __builtin_amdgcn_rcpf(v0);
    float r1 = __builtin_amdgcn_rcpf(v1);

    __threadfence_block();                      // LDS visibility within wave

    // ns[128] @ W1[128,16] for both nodes, sharing the W1t fragment.
    const float4* a0p = (const float4*)(&AHs[w][0][j * 32]);
    const float4* a1p = (const float4*)(&AHs[w][1][j * 32]);
    const float4* w1p = (const float4*)(W1t + c * D1 + j * 32);
    float p0 = 0.0f, p1 = 0.0f;
#pragma unroll
    for (int tt = 0; tt < 8; tt++) {
        float4 wv = w1p[tt];
        float4 x0 = a0p[tt];
        float4 x1 = a1p[tt];
        p0 += x0.x * wv.x + x0.y * wv.y + x0.z * wv.z + x0.w * wv.w;
        p1 += x1.x * wv.x + x1.y * wv.y + x1.z * wv.z + x1.w * wv.w;
    }
    p0 += __shfl_xor(p0, 16, 64);
    p0 += __shfl_xor(p0, 32, 64);
    p1 += __shfl_xor(p1, 16, 64);
    p1 += __shfl_xor(p1, 32, 64);
    if (lane < D2) {
        float bb = b1[c];
        float o0 = bb + p0 * r0;
        float o1 = bb + p1 * r1;
        float cl0 = fminf(fmaxf(o0, CLAMP_LO), CLAMP_HI);   // relu + next clip
        float cl1 = fminf(fmaxf(o1, CLAMP_LO), CLAMP_HI);
        Hp2[(size_t)n0 * D2 + c] = cl0 * cl0;
        Hp2[(size_t)n1 * D2 + c] = cl1 * cl1;
    }
}

// S2[e,:] = sum over 32 nodes of Hp2[node,:] (d=16, fp32).
__global__ __launch_bounds__(256) void k_edge_sum2(const float* __restrict__ Hp2,
                                                   const int* __restrict__ idx,
                                                   float* __restrict__ S2, int E) {
    int e = blockIdx.x * 16 + (threadIdx.x >> 4);
    int col = threadIdx.x & 15;
    if (e >= E) return;
    float acc = 0.0f;
#pragma unroll
    for (int j = 0; j < K_EDGE; j++) {
        int n = idx[e * K_EDGE + j];
        acc += Hp2[(size_t)n * D2 + col];
    }
    S2[(size_t)e * D2 + col] = acc;
}

// Fused layer-2 node kernel. TWO nodes per wave: node = lane bit 5, two
// 16-lane subgroups per node split the 16 gather slots. uint16 lst.
// Degree-adaptive: 4+4 slot blocks gated by max(dg0,dg1) (wave-uniform).
__global__ __launch_bounds__(256) void k_node2(const float* __restrict__ Hp2,
                                               const float* __restrict__ S2,
                                               const int* __restrict__ deg,
                                               const ushort_t* __restrict__ lst,
                                               const float* __restrict__ W2,
                                               const float* __restrict__ b2,
                                               float* __restrict__ out, int N, int E) {
    int w = threadIdx.x >> 6;
    int lane = threadIdx.x & 63;
    int pair = blockIdx.x * 4 + w;
    int n0 = pair * 2, n1 = n0 + 1;
    int col = lane & 15;
    int node = lane >> 5;                       // 0 or 1
    int gg = (lane >> 4) & 1;                   // subgroup within node
    int nn = node ? n1 : n0;

    int2 dg2 = ((const int2*)deg)[pair];
    int dg0 = min(dg2.x, CAP), dg1 = min(dg2.y, CAP);
    int sl = lane & 15;
    ushort_t idu = (lane < 32) ? lst[((lane < 16) ? n0 : n1) * CAP + sl] : (ushort_t)0;
    int dsel = (lane < 16) ? dg0 : dg1;
    int e_sel = (lane < 32 && sl < dsel) ? (int)idu : E;   // E = zero row of S2

    float hp = Hp2[(size_t)nn * D2 + col];
    int dgn = node ? dg1 : dg0;
    int dm = max(dg0, dg1);

    float acc = 0.0f;
    // block 1: slots {2t+gg}, t=0..3 -> covers deg <= 8
    {
        int ev[4];
#pragma unroll
        for (int t = 0; t < 4; t++) ev[t] = __shfl(e_sel, node * 16 + 2 * t + gg, 64);
        float sv[4];
#pragma unroll
        for (int t = 0; t < 4; t++) sv[t] = S2[(size_t)ev[t] * D2 + col];
#pragma unroll
        for (int t = 0; t < 4; t++)
            acc += __builtin_amdgcn_sqrtf(fmaxf(sv[t] - hp, 0.0f));
    }
    // block 2: slots {2t+gg}, t=4..7 (only when some node has deg > 8)
    if (dm > 8) {
        int ev[4];
#pragma unroll
        for (int t = 0; t < 4; t++) ev[t] = __shfl(e_sel, node * 16 + 2 * (4 + t) + gg, 64);
        float sv[4];
#pragma unroll
        for (int t = 0; t < 4; t++) sv[t] = S2[(size_t)ev[t] * D2 + col];
#pragma unroll
        for (int t = 0; t < 4; t++)
            acc += __builtin_amdgcn_sqrtf(fmaxf(sv[t] - hp, 0.0f));
    }
    for (int t = 16; t < dgn; t++) {            // rare tail; add once (gg==0)
        int e = lst[nn * CAP + t];
        float s = S2[(size_t)e * D2 + col];
        if (gg == 0) acc += __builtin_amdgcn_sqrtf(fmaxf(s - hp, 0.0f));
    }
    acc += __shfl_xor(acc, 16, 64);             // combine the node's 2 subgroups
    float ns = __builtin_amdgcn_sqrtf(hp) + acc * SQRT_INV31;

    float v = ns;
#pragma unroll
    for (int m = 1; m < 16; m <<= 1) v += __shfl_xor(v, m, 64);  // rowsum (16 cols)
    float r = __builtin_amdgcn_rcpf(v);

    __shared__ float AHs[4][2][D2];             // wave-private
    if (gg == 0) AHs[w][node][col] = ns * r;
    __threadfence_block();

    if (lane < C_OUT) {
        float o0 = b2[lane], o1 = o0;
#pragma unroll
        for (int i = 0; i < D2; i++) {
            float wv = W2[i * C_OUT + lane];
            o0 += AHs[w][0][i] * wv;
            o1 += AHs[w][1][i] * wv;
        }
        out[(size_t)n0 * C_OUT + lane] = o0;
        out[(size_t)n1 * C_OUT + lane] = o1;
    }
}

extern "C" void kernel_launch(void* const* d_in, const int* in_sizes, int n_in,
                              void* d_out, int out_size, void* d_ws, size_t ws_size,
                              hipStream_t stream) {
    const float* x   = (const float*)d_in[0];
    const int*   idx = (const int*)d_in[1];
    const float* W1  = (const float*)d_in[2];
    const float* b1  = (const float*)d_in[3];
    const float* W2  = (const float*)d_in[4];
    const float* b2  = (const float*)d_in[5];
    float* out = (float*)d_out;

    int N = in_sizes[0] / D1;     // 100000
    int E = in_sizes[1] / K_EDGE; // 25000

    // workspace layout (S and S2 have one extra zero row at index E)
    __half2* Hp = (__half2*)d_ws;                          // N*64 half2
    __half2* S  = Hp + (size_t)N * 64;                     // (E+1)*64 half2
    float* Hp2  = (float*)(S + (size_t)(E + 1) * 64);      // N*16 fp32
    float* S2   = Hp2 + (size_t)N * D2;                    // (E+1)*16 fp32
    float* W1t  = S2 + (size_t)(E + 1) * D2;               // 16*128 fp32
    int*   deg  = (int*)(W1t + D1 * D2);                   // N ints
    ushort_t* lst = (ushort_t*)(deg + N);                  // N*CAP uint16

    int total = E * K_EDGE;        // 800000
    int n4 = N * D1 / 4;           // 3200000

    (void)hipMemsetAsync(deg, 0, (size_t)N * sizeof(int), stream);
    k_setup<<<(n4 + 255) / 256, 256, 0, stream>>>(x, Hp, idx, deg, lst, W1, W1t,
                                                  S, S2, n4, total, E);
    k_edge_sum<<<E / 8, 256, 0, stream>>>(Hp, idx, S, E);
    k_node1<<<N / 8, 256, 0, stream>>>(Hp, S, deg, lst, W1t, b1, Hp2, N, E);
    k_edge_sum2<<<(E + 15) / 16, 256, 0, stream>>>(Hp2, idx, S2, E);
    k_node2<<<N / 8, 256, 0, stream>>>(Hp2, S2, deg, lst, W2, b2, out, N, E);
}